// Round 22
// baseline (172.985 us; speedup 1.0000x reference)
//
#include <hip/hip_runtime.h>

#define L2E 1.44269504088896340736f   // log2(e)
#define LN2 0.69314718055994530942f

// Raw HW transcendentals: v_exp_f32 = 2^x, v_log_f32 = log2(x).
#define EXP2F(x) __builtin_amdgcn_exp2f(x)
#define LOG2F(x) __builtin_amdgcn_logf(x)

// Probability-domain soft-min DP; R17 machine with three fixes:
//  (1) VOLATILE slot loads: R17's "memory"-clobber pinning was defeated by
//      const/__restrict invariance (proof: VGPR=76 < the >=106 needed for a
//      live 16-deep pipeline).  Volatile ops are pinned in program order ->
//      the 16-step load->convert distance finally exists in the schedule.
//  (2) deferred shfl consumption: pd1's cndmask moved to the NEXT step's
//      top (carry raw nxCarry) -> ds_bpermute gets a full step of slack
//      (was consumed ~20 instrs after issue in every round since R7).
//  (3) parity renaming: w banks (A/B by step parity), c/n banks (X/Y by
//      rotation parity, all compile-time), pd rename chain -> ~12 fewer
//      reg moves/step; junk mask folded into exp2 via -inf fma bias.
// Semantics byte-identical to R17 (verified absmax 0): same cols, clamps,
// junk rule (colr > 268), renorm every 64 diags (exact 2^-e, sig -= e).

typedef float f4 __attribute__((ext_vector_type(4)));

template <int I> __device__ __forceinline__ float comp(const f4 v) {
    if constexpr (I == 0) return v.x;
    else if constexpr (I == 1) return v.y;
    else if constexpr (I == 2) return v.z;
    else return v.w;
}

__device__ __forceinline__ f4 g4f(const f4 v) {
    f4 r;
    r.x = EXP2F(v.x * -L2E); r.y = EXP2F(v.y * -L2E);
    r.z = EXP2F(v.z * -L2E); r.w = EXP2F(v.w * -L2E);
    return r;
}

template <int JJ>
__device__ __forceinline__ void stepf(
    int kbmt, bool t0, const float* __restrict__ Cb,
    int rb0, int rb1, int rb2, int rb3,
    f4& X0, f4& X1, f4& X2, f4& X3,
    f4& Y0, f4& Y1, f4& Y2, f4& Y3,
    f4& s00, f4& s01, f4& s02, f4& s03,
    f4& s10, f4& s11, f4& s12, f4& s13,
    f4& s20, f4& s21, f4& s22, f4& s23,
    f4& s30, f4& s31, f4& s32, f4& s33,
    float& wA0, float& wA1, float& wA2, float& wA3,
    float& wB0, float& wB1, float& wB2, float& wB3,
    float& pdPrev, float& nxCarry)
{
    constexpr int P  = JJ & 3;
    constexpr int SB = (JJ >> 2) & 3;
    constexpr bool EV = (JJ & 1) == 0;
    // parity of the last rotation of row i (valid for JJ-i >= -3)
    constexpr int p0 = ((JJ - 0 + 16) >> 2) & 1;
    constexpr int p1 = ((JJ - 1 + 16) >> 2) & 1;
    constexpr int p2 = ((JJ - 2 + 16) >> 2) & 1;
    constexpr int p3 = ((JJ - 3 + 16) >> 2) & 1;

    f4& cb0 = p0 ? X0 : Y0;          // consumable (post-rotation) quad, row 0
    f4& cb1 = p1 ? X1 : Y1;
    f4& cb2 = p2 ? X2 : Y2;
    f4& cb3 = p3 ? X3 : Y3;
    f4& tgt = (P == 0) ? (p0 ? Y0 : X0)
            : (P == 1) ? (p1 ? Y1 : X1)
            : (P == 2) ? (p2 ? Y2 : X2)
                       : (p3 ? Y3 : X3);   // rotation write bank (old c)

    f4& sP =
        (SB == 0) ? ((P == 0) ? s00 : (P == 1) ? s01 : (P == 2) ? s02 : s03)
      : (SB == 1) ? ((P == 0) ? s10 : (P == 1) ? s11 : (P == 2) ? s12 : s13)
      : (SB == 2) ? ((P == 0) ? s20 : (P == 1) ? s21 : (P == 2) ? s22 : s23)
                  : ((P == 0) ? s30 : (P == 1) ? s31 : (P == 2) ? s32 : s33);

    // w banks: even J reads w1=A,w2=B and writes B; odd J the reverse
    float& r10 = EV ? wA0 : wB0;  float& r11 = EV ? wA1 : wB1;
    float& r12 = EV ? wA2 : wB2;  float& r13 = EV ? wA3 : wB3;
    float& o0  = EV ? wB0 : wA0;  float& o1  = EV ? wB1 : wA1;
    float& o2  = EV ? wB2 : wA2;  float& o3  = EV ? wB3 : wA3;

    const int colr = kbmt + (JJ + 20 - P);
    const int col  = colr < 0 ? 0 : (colr > 252 ? 252 : colr);
    const int rb   = (P == 0) ? rb0 : (P == 1) ? rb1 : (P == 2) ? rb2 : rb3;

    // pd1(J): masked shfl result carried from step J-1 (full-step slack)
    const float pd1v = t0 ? 0.0f : nxCarry;

    const float g0 = comp<(P    ) & 3>(cb0);
    const float g1 = comp<(P + 3) & 3>(cb1);
    const float g2 = comp<(P + 2) & 3>(cb2);
    const float g3 = comp<(P + 1) & 3>(cb3);
    const float e0 = g0 * (r10 + pd1v + pdPrev);
    const float e1 = g1 * (r11 + r10 + o0);
    const float e2 = g2 * (r12 + r11 + o1);
    const float e3 = g3 * (r13 + r12 + o2);

    nxCarry = __shfl_up(e3, 1);      // consumed at step J+1's top
    pdPrev  = pd1v;

    // conversion of the slot loaded 16 steps ago; junk folded in as -inf
    // bias: exp2(x*-L2E + -inf) == 0 exactly.
    const float bias = (colr > 268) ? __int_as_float(0xff800000) : 0.0f;
    f4 gq;
    gq.x = EXP2F(fmaf(sP.x, -L2E, bias));
    gq.y = EXP2F(fmaf(sP.y, -L2E, bias));
    gq.z = EXP2F(fmaf(sP.z, -L2E, bias));
    gq.w = EXP2F(fmaf(sP.w, -L2E, bias));
    tgt = gq;

    // VOLATILE pinned refill: program-order load, cannot be sunk
    sP = *(volatile const f4*)(Cb + rb + col);

    o0 = e0; o1 = e1; o2 = e2; o3 = e3;

    asm volatile("" ::: "memory");   // step boundary
}

__global__ __launch_bounds__(64, 1) void dp_softmin_wave(const float* __restrict__ C,
                                                         float* __restrict__ out) {
    const int b = blockIdx.x;
    const int t = threadIdx.x;
    const float* Cb = C + ((size_t)b << 16);
    const int t4 = 4 * t;
    const bool t0 = (t == 0);

    const int rb0 = (t4 + 0) << 8;
    const int rb1 = (t4 + 1) << 8;
    const int rb2 = (t4 + 2) << 8;
    const int rb3 = (t4 + 3) << 8;

    auto cl = [](int c) { return c < 0 ? 0 : (c > 252 ? 252 : c); };
    auto q4 = [&](int rb, int col) { return *(const f4*)(Cb + rb + col); };

    // init = fixed point of the unconditional machine for kk <= 0 (R17):
    // row0: c-role = Y0 (col 0), n-role = X0 (cl(4-t4)); rows 1-3: X=Y=col 0
    f4 Y0 = g4f(q4(rb0, 0));
    f4 X0 = g4f(q4(rb0, cl(4 - t4)));
    f4 X1 = g4f(q4(rb1, 0)), Y1 = X1;
    f4 X2 = g4f(q4(rb2, 0)), Y2 = X2;
    f4 X3 = g4f(q4(rb3, 0)), Y3 = X3;

    f4 s00 = q4(rb0, cl(20 - t4));
    f4 s01 = q4(rb1, cl(4 - t4));
    f4 s02 = q4(rb2, cl(4 - t4));
    f4 s03 = q4(rb3, cl(4 - t4));
    f4 s10 = q4(rb0, cl(8 - t4)),  s11 = q4(rb1, cl(8 - t4));
    f4 s12 = q4(rb2, cl(8 - t4)),  s13 = q4(rb3, cl(8 - t4));
    f4 s20 = q4(rb0, cl(12 - t4)), s21 = q4(rb1, cl(12 - t4));
    f4 s22 = q4(rb2, cl(12 - t4)), s23 = q4(rb3, cl(12 - t4));
    f4 s30 = q4(rb0, cl(16 - t4)), s31 = q4(rb1, cl(16 - t4));
    f4 s32 = q4(rb2, cl(16 - t4)), s33 = q4(rb3, cl(16 - t4));

    // w banks: before step 1, logical w1 (diag 0) lives in B, w2 (=0) in A
    float wA0 = 0.0f, wA1 = 0.0f, wA2 = 0.0f, wA3 = 0.0f;
    float wB0 = t0 ? Y0.x : 0.0f, wB1 = 0.0f, wB2 = 0.0f, wB3 = 0.0f;
    float pdPrev = 0.0f, nxCarry = 0.0f;
    int sig = 0;

    asm volatile("" ::: "memory");

#define ARGS t0, Cb, rb0, rb1, rb2, rb3, X0,X1,X2,X3, Y0,Y1,Y2,Y3, \
             s00,s01,s02,s03, s10,s11,s12,s13, s20,s21,s22,s23, s30,s31,s32,s33, \
             wA0,wA1,wA2,wA3, wB0,wB1,wB2,wB3, pdPrev, nxCarry

    // prologue kk = 1..15 (kbmt = -t4)
    stepf<1>(-t4, ARGS);  stepf<2>(-t4, ARGS);  stepf<3>(-t4, ARGS);
    stepf<4>(-t4, ARGS);  stepf<5>(-t4, ARGS);  stepf<6>(-t4, ARGS);
    stepf<7>(-t4, ARGS);  stepf<8>(-t4, ARGS);  stepf<9>(-t4, ARGS);
    stepf<10>(-t4, ARGS); stepf<11>(-t4, ARGS); stepf<12>(-t4, ARGS);
    stepf<13>(-t4, ARGS); stepf<14>(-t4, ARGS); stepf<15>(-t4, ARGS);

#pragma clang loop unroll(disable)
    for (int kb = 16; kb <= 480; kb += 16) {
        if ((kb & 63) == 0) {
            // block-floating renorm: exact power-of-2, sig -= e
            float M = fmaxf(fmaxf(fmaxf(wA0, wA1), fmaxf(wA2, wA3)),
                            fmaxf(fmaxf(wB0, wB1), fmaxf(wB2, wB3)));
            #pragma unroll
            for (int m = 1; m < 64; m <<= 1) M = fmaxf(M, __shfl_xor(M, m));
            int e = ((__float_as_int(M) >> 23) & 255) - 127;
            float f = __int_as_float((127 - e) << 23);
            wA0 *= f; wA1 *= f; wA2 *= f; wA3 *= f;
            wB0 *= f; wB1 *= f; wB2 *= f; wB3 *= f;
            pdPrev *= f; nxCarry *= f;
            sig -= e;
        }
        const int kbmt = kb - t4;
        stepf<0>(kbmt, ARGS);  stepf<1>(kbmt, ARGS);  stepf<2>(kbmt, ARGS);
        stepf<3>(kbmt, ARGS);  stepf<4>(kbmt, ARGS);  stepf<5>(kbmt, ARGS);
        stepf<6>(kbmt, ARGS);  stepf<7>(kbmt, ARGS);  stepf<8>(kbmt, ARGS);
        stepf<9>(kbmt, ARGS);  stepf<10>(kbmt, ARGS); stepf<11>(kbmt, ARGS);
        stepf<12>(kbmt, ARGS); stepf<13>(kbmt, ARGS); stepf<14>(kbmt, ARGS);
        stepf<15>(kbmt, ARGS);
    }

    // epilogue kk = 496..510 (kbmt = 496 - t4)
    {
        const int kbmt = 496 - t4;
        stepf<0>(kbmt, ARGS);  stepf<1>(kbmt, ARGS);  stepf<2>(kbmt, ARGS);
        stepf<3>(kbmt, ARGS);  stepf<4>(kbmt, ARGS);  stepf<5>(kbmt, ARGS);
        stepf<6>(kbmt, ARGS);  stepf<7>(kbmt, ARGS);  stepf<8>(kbmt, ARGS);
        stepf<9>(kbmt, ARGS);  stepf<10>(kbmt, ARGS); stepf<11>(kbmt, ARGS);
        stepf<12>(kbmt, ARGS); stepf<13>(kbmt, ARGS); stepf<14>(kbmt, ARGS);
    }
#undef ARGS

    // corner (255,255): step 510 is even -> written into B bank; lane 63 wB3
    if (t == 63) out[b] = ((float)sig - LOG2F(wB3)) * LN2;
}

extern "C" void kernel_launch(void* const* d_in, const int* in_sizes, int n_in,
                              void* d_out, int out_size, void* d_ws, size_t ws_size,
                              hipStream_t stream) {
    const float* C = (const float*)d_in[0];
    float* out = (float*)d_out;
    dp_softmin_wave<<<512, 64, 0, stream>>>(C, out);
}

// Round 23
// 67.708 us; speedup vs baseline: 2.5549x; 2.5549x over previous
//
#include <hip/hip_runtime.h>

#define L2E 1.44269504088896340736f   // log2(e)
#define LN2 0.69314718055994530942f

// Raw HW transcendentals: v_exp_f32 = 2^x, v_log_f32 = log2(x).
#define EXP2F(x) __builtin_amdgcn_exp2f(x)
#define LOG2F(x) __builtin_amdgcn_logf(x)

// Probability-domain soft-min DP (R22 machine, verified absmax 0) with the
// ROOT-CAUSE fix for pipeline collapse:
//   C is a const/__restrict kernel arg with no stores -> AMDGPU marks its
//   loads invariant/noclobber, and invariant loads legally cross ANY
//   asm "memory" barrier.  Every pinning attempt since R16 was defeated by
//   this (proof: VGPR stuck at 76-80 < the >=106 a live 16-deep pipeline
//   needs, regardless of barriers/volatile/reordering).
//   FIX: launder the base pointer through an opaque asm ("+s") at entry --
//   provenance becomes unknown, loads lose invariance, and the existing
//   per-step memory-clobber barriers finally pin each load in its step.
//   The 16-deep load->convert distance then exists in hardware, with
//   compiler-emitted counted s_waitcnt vmcnt(15) at each conversion.
// Everything else identical to R22: parity-renamed banks (X/Y quads, A/B
// w-banks), deferred shfl consumption (nxCarry), -inf-bias junk fold,
// renorm every 64 diags (exact 2^-e, sig -= e).

typedef float f4 __attribute__((ext_vector_type(4)));

template <int I> __device__ __forceinline__ float comp(const f4 v) {
    if constexpr (I == 0) return v.x;
    else if constexpr (I == 1) return v.y;
    else if constexpr (I == 2) return v.z;
    else return v.w;
}

__device__ __forceinline__ f4 g4f(const f4 v) {
    f4 r;
    r.x = EXP2F(v.x * -L2E); r.y = EXP2F(v.y * -L2E);
    r.z = EXP2F(v.z * -L2E); r.w = EXP2F(v.w * -L2E);
    return r;
}

template <int JJ>
__device__ __forceinline__ void stepf(
    int kbmt, bool t0, const float* Cb,
    int rb0, int rb1, int rb2, int rb3,
    f4& X0, f4& X1, f4& X2, f4& X3,
    f4& Y0, f4& Y1, f4& Y2, f4& Y3,
    f4& s00, f4& s01, f4& s02, f4& s03,
    f4& s10, f4& s11, f4& s12, f4& s13,
    f4& s20, f4& s21, f4& s22, f4& s23,
    f4& s30, f4& s31, f4& s32, f4& s33,
    float& wA0, float& wA1, float& wA2, float& wA3,
    float& wB0, float& wB1, float& wB2, float& wB3,
    float& pdPrev, float& nxCarry)
{
    constexpr int P  = JJ & 3;
    constexpr int SB = (JJ >> 2) & 3;
    constexpr bool EV = (JJ & 1) == 0;
    // parity of the last rotation of row i (valid for JJ-i >= -3)
    constexpr int p0 = ((JJ - 0 + 16) >> 2) & 1;
    constexpr int p1 = ((JJ - 1 + 16) >> 2) & 1;
    constexpr int p2 = ((JJ - 2 + 16) >> 2) & 1;
    constexpr int p3 = ((JJ - 3 + 16) >> 2) & 1;

    f4& cb0 = p0 ? X0 : Y0;          // consumable (post-rotation) quad, row 0
    f4& cb1 = p1 ? X1 : Y1;
    f4& cb2 = p2 ? X2 : Y2;
    f4& cb3 = p3 ? X3 : Y3;
    f4& tgt = (P == 0) ? (p0 ? Y0 : X0)
            : (P == 1) ? (p1 ? Y1 : X1)
            : (P == 2) ? (p2 ? Y2 : X2)
                       : (p3 ? Y3 : X3);   // rotation write bank (old c)

    f4& sP =
        (SB == 0) ? ((P == 0) ? s00 : (P == 1) ? s01 : (P == 2) ? s02 : s03)
      : (SB == 1) ? ((P == 0) ? s10 : (P == 1) ? s11 : (P == 2) ? s12 : s13)
      : (SB == 2) ? ((P == 0) ? s20 : (P == 1) ? s21 : (P == 2) ? s22 : s23)
                  : ((P == 0) ? s30 : (P == 1) ? s31 : (P == 2) ? s32 : s33);

    // w banks: even J reads w1=A,w2=B and writes B; odd J the reverse
    float& r10 = EV ? wA0 : wB0;  float& r11 = EV ? wA1 : wB1;
    float& r12 = EV ? wA2 : wB2;  float& r13 = EV ? wA3 : wB3;
    float& o0  = EV ? wB0 : wA0;  float& o1  = EV ? wB1 : wA1;
    float& o2  = EV ? wB2 : wA2;  float& o3  = EV ? wB3 : wA3;

    const int colr = kbmt + (JJ + 20 - P);
    const int col  = colr < 0 ? 0 : (colr > 252 ? 252 : colr);
    const int rb   = (P == 0) ? rb0 : (P == 1) ? rb1 : (P == 2) ? rb2 : rb3;

    // pd1(J): masked shfl result carried from step J-1 (full-step slack)
    const float pd1v = t0 ? 0.0f : nxCarry;

    const float g0 = comp<(P    ) & 3>(cb0);
    const float g1 = comp<(P + 3) & 3>(cb1);
    const float g2 = comp<(P + 2) & 3>(cb2);
    const float g3 = comp<(P + 1) & 3>(cb3);
    const float e0 = g0 * (r10 + pd1v + pdPrev);
    const float e1 = g1 * (r11 + r10 + o0);
    const float e2 = g2 * (r12 + r11 + o1);
    const float e3 = g3 * (r13 + r12 + o2);

    nxCarry = __shfl_up(e3, 1);      // consumed at step J+1's top
    pdPrev  = pd1v;

    // conversion of the slot loaded 16 steps ago; junk folded in as -inf
    // bias: exp2(x*-L2E + -inf) == 0 exactly.
    const float bias = (colr > 268) ? __int_as_float(0xff800000) : 0.0f;
    f4 gq;
    gq.x = EXP2F(fmaf(sP.x, -L2E, bias));
    gq.y = EXP2F(fmaf(sP.y, -L2E, bias));
    gq.z = EXP2F(fmaf(sP.z, -L2E, bias));
    gq.w = EXP2F(fmaf(sP.w, -L2E, bias));
    tgt = gq;

    // refill: plain load through the LAUNDERED pointer -> not invariant ->
    // pinned in this step by the boundary barrier below.
    sP = *(const f4*)(Cb + rb + col);

    o0 = e0; o1 = e1; o2 = e2; o3 = e3;

    asm volatile("" ::: "memory");   // step boundary (now actually pins loads)
}

__global__ __launch_bounds__(64, 1) void dp_softmin_wave(const float* __restrict__ C,
                                                         float* __restrict__ out) {
    const int b = blockIdx.x;
    const int t = threadIdx.x;
    const float* Cb = C + ((size_t)b << 16);
    // LAUNDER: opaque provenance -> loads through Cb lose invariant/noclobber
    // status -> asm "memory" barriers can finally order them.
    asm volatile("" : "+s"(Cb));
    const int t4 = 4 * t;
    const bool t0 = (t == 0);

    const int rb0 = (t4 + 0) << 8;
    const int rb1 = (t4 + 1) << 8;
    const int rb2 = (t4 + 2) << 8;
    const int rb3 = (t4 + 3) << 8;

    auto cl = [](int c) { return c < 0 ? 0 : (c > 252 ? 252 : c); };
    auto q4 = [&](int rb, int col) { return *(const f4*)(Cb + rb + col); };

    // init = fixed point of the unconditional machine for kk <= 0 (R17):
    // row0: c-role = Y0 (col 0), n-role = X0 (cl(4-t4)); rows 1-3: X=Y=col 0
    f4 Y0 = g4f(q4(rb0, 0));
    f4 X0 = g4f(q4(rb0, cl(4 - t4)));
    f4 X1 = g4f(q4(rb1, 0)), Y1 = X1;
    f4 X2 = g4f(q4(rb2, 0)), Y2 = X2;
    f4 X3 = g4f(q4(rb3, 0)), Y3 = X3;

    f4 s00 = q4(rb0, cl(20 - t4));
    f4 s01 = q4(rb1, cl(4 - t4));
    f4 s02 = q4(rb2, cl(4 - t4));
    f4 s03 = q4(rb3, cl(4 - t4));
    f4 s10 = q4(rb0, cl(8 - t4)),  s11 = q4(rb1, cl(8 - t4));
    f4 s12 = q4(rb2, cl(8 - t4)),  s13 = q4(rb3, cl(8 - t4));
    f4 s20 = q4(rb0, cl(12 - t4)), s21 = q4(rb1, cl(12 - t4));
    f4 s22 = q4(rb2, cl(12 - t4)), s23 = q4(rb3, cl(12 - t4));
    f4 s30 = q4(rb0, cl(16 - t4)), s31 = q4(rb1, cl(16 - t4));
    f4 s32 = q4(rb2, cl(16 - t4)), s33 = q4(rb3, cl(16 - t4));

    // w banks: before step 1, logical w1 (diag 0) lives in B, w2 (=0) in A
    float wA0 = 0.0f, wA1 = 0.0f, wA2 = 0.0f, wA3 = 0.0f;
    float wB0 = t0 ? Y0.x : 0.0f, wB1 = 0.0f, wB2 = 0.0f, wB3 = 0.0f;
    float pdPrev = 0.0f, nxCarry = 0.0f;
    int sig = 0;

    asm volatile("" ::: "memory");

#define ARGS t0, Cb, rb0, rb1, rb2, rb3, X0,X1,X2,X3, Y0,Y1,Y2,Y3, \
             s00,s01,s02,s03, s10,s11,s12,s13, s20,s21,s22,s23, s30,s31,s32,s33, \
             wA0,wA1,wA2,wA3, wB0,wB1,wB2,wB3, pdPrev, nxCarry

    // prologue kk = 1..15 (kbmt = -t4)
    stepf<1>(-t4, ARGS);  stepf<2>(-t4, ARGS);  stepf<3>(-t4, ARGS);
    stepf<4>(-t4, ARGS);  stepf<5>(-t4, ARGS);  stepf<6>(-t4, ARGS);
    stepf<7>(-t4, ARGS);  stepf<8>(-t4, ARGS);  stepf<9>(-t4, ARGS);
    stepf<10>(-t4, ARGS); stepf<11>(-t4, ARGS); stepf<12>(-t4, ARGS);
    stepf<13>(-t4, ARGS); stepf<14>(-t4, ARGS); stepf<15>(-t4, ARGS);

#pragma clang loop unroll(disable)
    for (int kb = 16; kb <= 480; kb += 16) {
        if ((kb & 63) == 0) {
            // block-floating renorm: exact power-of-2, sig -= e
            float M = fmaxf(fmaxf(fmaxf(wA0, wA1), fmaxf(wA2, wA3)),
                            fmaxf(fmaxf(wB0, wB1), fmaxf(wB2, wB3)));
            #pragma unroll
            for (int m = 1; m < 64; m <<= 1) M = fmaxf(M, __shfl_xor(M, m));
            int e = ((__float_as_int(M) >> 23) & 255) - 127;
            float f = __int_as_float((127 - e) << 23);
            wA0 *= f; wA1 *= f; wA2 *= f; wA3 *= f;
            wB0 *= f; wB1 *= f; wB2 *= f; wB3 *= f;
            pdPrev *= f; nxCarry *= f;
            sig -= e;
        }
        const int kbmt = kb - t4;
        stepf<0>(kbmt, ARGS);  stepf<1>(kbmt, ARGS);  stepf<2>(kbmt, ARGS);
        stepf<3>(kbmt, ARGS);  stepf<4>(kbmt, ARGS);  stepf<5>(kbmt, ARGS);
        stepf<6>(kbmt, ARGS);  stepf<7>(kbmt, ARGS);  stepf<8>(kbmt, ARGS);
        stepf<9>(kbmt, ARGS);  stepf<10>(kbmt, ARGS); stepf<11>(kbmt, ARGS);
        stepf<12>(kbmt, ARGS); stepf<13>(kbmt, ARGS); stepf<14>(kbmt, ARGS);
        stepf<15>(kbmt, ARGS);
    }

    // epilogue kk = 496..510 (kbmt = 496 - t4)
    {
        const int kbmt = 496 - t4;
        stepf<0>(kbmt, ARGS);  stepf<1>(kbmt, ARGS);  stepf<2>(kbmt, ARGS);
        stepf<3>(kbmt, ARGS);  stepf<4>(kbmt, ARGS);  stepf<5>(kbmt, ARGS);
        stepf<6>(kbmt, ARGS);  stepf<7>(kbmt, ARGS);  stepf<8>(kbmt, ARGS);
        stepf<9>(kbmt, ARGS);  stepf<10>(kbmt, ARGS); stepf<11>(kbmt, ARGS);
        stepf<12>(kbmt, ARGS); stepf<13>(kbmt, ARGS); stepf<14>(kbmt, ARGS);
    }
#undef ARGS

    // corner (255,255): step 510 is even -> written into B bank; lane 63 wB3
    if (t == 63) out[b] = ((float)sig - LOG2F(wB3)) * LN2;
}

extern "C" void kernel_launch(void* const* d_in, const int* in_sizes, int n_in,
                              void* d_out, int out_size, void* d_ws, size_t ws_size,
                              hipStream_t stream) {
    const float* C = (const float*)d_in[0];
    float* out = (float*)d_out;
    dp_softmin_wave<<<512, 64, 0, stream>>>(C, out);
}

// Round 24
// 67.107 us; speedup vs baseline: 2.5778x; 1.0090x over previous
//
#include <hip/hip_runtime.h>

#define L2E 1.44269504088896340736f   // log2(e)
#define LN2 0.69314718055994530942f

// Raw HW transcendentals: v_exp_f32 = 2^x, v_log_f32 = log2(x).
#define EXP2F(x) __builtin_amdgcn_exp2f(x)
#define LOG2F(x) __builtin_amdgcn_logf(x)

// Probability-domain soft-min DP (R23 machine, verified absmax 0) with ONE
// change: the per-step lane-boundary transfer uses DPP wave_shr:1 (a single
// VALU op, ~4cy, no LDS pipe) instead of __shfl_up (ds_bpermute, ~120cy
// round trip on the serial chain every step since R7).
//   lane t <- lane t-1:  v_mov_b32_dpp wave_shr:1  == shfl_up(1)
//   __builtin_amdgcn_update_dpp(old=0, src, 0x138 /*wave_shr:1*/, 0xf, 0xf,
//   false) -> lane 0 receives old=0 (and the t0 mask still applies).
// Everything else identical to R23: parity-renamed banks, deferred boundary
// consumption (nxCarry), -inf-bias junk fold, 16-deep slot ring, renorm
// every 64 diags (exact 2^-e, sig -= e), laundered base pointer.

typedef float f4 __attribute__((ext_vector_type(4)));

template <int I> __device__ __forceinline__ float comp(const f4 v) {
    if constexpr (I == 0) return v.x;
    else if constexpr (I == 1) return v.y;
    else if constexpr (I == 2) return v.z;
    else return v.w;
}

__device__ __forceinline__ f4 g4f(const f4 v) {
    f4 r;
    r.x = EXP2F(v.x * -L2E); r.y = EXP2F(v.y * -L2E);
    r.z = EXP2F(v.z * -L2E); r.w = EXP2F(v.w * -L2E);
    return r;
}

// whole-wave shift toward higher lanes by 1 (== __shfl_up(x,1)), pure VALU
__device__ __forceinline__ float wave_shr1(float x) {
    return __int_as_float(
        __builtin_amdgcn_update_dpp(0, __float_as_int(x),
                                    0x138 /*wave_shr:1*/, 0xF, 0xF, false));
}

template <int JJ>
__device__ __forceinline__ void stepf(
    int kbmt, bool t0, const float* Cb,
    int rb0, int rb1, int rb2, int rb3,
    f4& X0, f4& X1, f4& X2, f4& X3,
    f4& Y0, f4& Y1, f4& Y2, f4& Y3,
    f4& s00, f4& s01, f4& s02, f4& s03,
    f4& s10, f4& s11, f4& s12, f4& s13,
    f4& s20, f4& s21, f4& s22, f4& s23,
    f4& s30, f4& s31, f4& s32, f4& s33,
    float& wA0, float& wA1, float& wA2, float& wA3,
    float& wB0, float& wB1, float& wB2, float& wB3,
    float& pdPrev, float& nxCarry)
{
    constexpr int P  = JJ & 3;
    constexpr int SB = (JJ >> 2) & 3;
    constexpr bool EV = (JJ & 1) == 0;
    // parity of the last rotation of row i (valid for JJ-i >= -3)
    constexpr int p0 = ((JJ - 0 + 16) >> 2) & 1;
    constexpr int p1 = ((JJ - 1 + 16) >> 2) & 1;
    constexpr int p2 = ((JJ - 2 + 16) >> 2) & 1;
    constexpr int p3 = ((JJ - 3 + 16) >> 2) & 1;

    f4& cb0 = p0 ? X0 : Y0;          // consumable (post-rotation) quad, row 0
    f4& cb1 = p1 ? X1 : Y1;
    f4& cb2 = p2 ? X2 : Y2;
    f4& cb3 = p3 ? X3 : Y3;
    f4& tgt = (P == 0) ? (p0 ? Y0 : X0)
            : (P == 1) ? (p1 ? Y1 : X1)
            : (P == 2) ? (p2 ? Y2 : X2)
                       : (p3 ? Y3 : X3);   // rotation write bank (old c)

    f4& sP =
        (SB == 0) ? ((P == 0) ? s00 : (P == 1) ? s01 : (P == 2) ? s02 : s03)
      : (SB == 1) ? ((P == 0) ? s10 : (P == 1) ? s11 : (P == 2) ? s12 : s13)
      : (SB == 2) ? ((P == 0) ? s20 : (P == 1) ? s21 : (P == 2) ? s22 : s23)
                  : ((P == 0) ? s30 : (P == 1) ? s31 : (P == 2) ? s32 : s33);

    // w banks: even J reads w1=A,w2=B and writes B; odd J the reverse
    float& r10 = EV ? wA0 : wB0;  float& r11 = EV ? wA1 : wB1;
    float& r12 = EV ? wA2 : wB2;  float& r13 = EV ? wA3 : wB3;
    float& o0  = EV ? wB0 : wA0;  float& o1  = EV ? wB1 : wA1;
    float& o2  = EV ? wB2 : wA2;  float& o3  = EV ? wB3 : wA3;

    const int colr = kbmt + (JJ + 20 - P);
    const int col  = colr < 0 ? 0 : (colr > 252 ? 252 : colr);
    const int rb   = (P == 0) ? rb0 : (P == 1) ? rb1 : (P == 2) ? rb2 : rb3;

    // pd1(J): masked boundary value carried from step J-1
    const float pd1v = t0 ? 0.0f : nxCarry;

    const float g0 = comp<(P    ) & 3>(cb0);
    const float g1 = comp<(P + 3) & 3>(cb1);
    const float g2 = comp<(P + 2) & 3>(cb2);
    const float g3 = comp<(P + 1) & 3>(cb3);
    const float e0 = g0 * (r10 + pd1v + pdPrev);
    const float e1 = g1 * (r11 + r10 + o0);
    const float e2 = g2 * (r12 + r11 + o1);
    const float e3 = g3 * (r13 + r12 + o2);

    nxCarry = wave_shr1(e3);         // single VALU op; consumed at J+1's top
    pdPrev  = pd1v;

    // conversion of the slot loaded 16 steps ago; junk folded in as -inf
    // bias: exp2(x*-L2E + -inf) == 0 exactly.
    const float bias = (colr > 268) ? __int_as_float(0xff800000) : 0.0f;
    f4 gq;
    gq.x = EXP2F(fmaf(sP.x, -L2E, bias));
    gq.y = EXP2F(fmaf(sP.y, -L2E, bias));
    gq.z = EXP2F(fmaf(sP.z, -L2E, bias));
    gq.w = EXP2F(fmaf(sP.w, -L2E, bias));
    tgt = gq;

    // refill through the laundered pointer
    sP = *(const f4*)(Cb + rb + col);

    o0 = e0; o1 = e1; o2 = e2; o3 = e3;

    asm volatile("" ::: "memory");   // step boundary
}

__global__ __launch_bounds__(64, 1) void dp_softmin_wave(const float* __restrict__ C,
                                                         float* __restrict__ out) {
    const int b = blockIdx.x;
    const int t = threadIdx.x;
    const float* Cb = C + ((size_t)b << 16);
    asm volatile("" : "+s"(Cb));     // opaque provenance
    const int t4 = 4 * t;
    const bool t0 = (t == 0);

    const int rb0 = (t4 + 0) << 8;
    const int rb1 = (t4 + 1) << 8;
    const int rb2 = (t4 + 2) << 8;
    const int rb3 = (t4 + 3) << 8;

    auto cl = [](int c) { return c < 0 ? 0 : (c > 252 ? 252 : c); };
    auto q4 = [&](int rb, int col) { return *(const f4*)(Cb + rb + col); };

    // init = fixed point of the unconditional machine for kk <= 0 (R17):
    // row0: c-role = Y0 (col 0), n-role = X0 (cl(4-t4)); rows 1-3: X=Y=col 0
    f4 Y0 = g4f(q4(rb0, 0));
    f4 X0 = g4f(q4(rb0, cl(4 - t4)));
    f4 X1 = g4f(q4(rb1, 0)), Y1 = X1;
    f4 X2 = g4f(q4(rb2, 0)), Y2 = X2;
    f4 X3 = g4f(q4(rb3, 0)), Y3 = X3;

    f4 s00 = q4(rb0, cl(20 - t4));
    f4 s01 = q4(rb1, cl(4 - t4));
    f4 s02 = q4(rb2, cl(4 - t4));
    f4 s03 = q4(rb3, cl(4 - t4));
    f4 s10 = q4(rb0, cl(8 - t4)),  s11 = q4(rb1, cl(8 - t4));
    f4 s12 = q4(rb2, cl(8 - t4)),  s13 = q4(rb3, cl(8 - t4));
    f4 s20 = q4(rb0, cl(12 - t4)), s21 = q4(rb1, cl(12 - t4));
    f4 s22 = q4(rb2, cl(12 - t4)), s23 = q4(rb3, cl(12 - t4));
    f4 s30 = q4(rb0, cl(16 - t4)), s31 = q4(rb1, cl(16 - t4));
    f4 s32 = q4(rb2, cl(16 - t4)), s33 = q4(rb3, cl(16 - t4));

    // w banks: before step 1, logical w1 (diag 0) lives in B, w2 (=0) in A
    float wA0 = 0.0f, wA1 = 0.0f, wA2 = 0.0f, wA3 = 0.0f;
    float wB0 = t0 ? Y0.x : 0.0f, wB1 = 0.0f, wB2 = 0.0f, wB3 = 0.0f;
    float pdPrev = 0.0f, nxCarry = 0.0f;
    int sig = 0;

    asm volatile("" ::: "memory");

#define ARGS t0, Cb, rb0, rb1, rb2, rb3, X0,X1,X2,X3, Y0,Y1,Y2,Y3, \
             s00,s01,s02,s03, s10,s11,s12,s13, s20,s21,s22,s23, s30,s31,s32,s33, \
             wA0,wA1,wA2,wA3, wB0,wB1,wB2,wB3, pdPrev, nxCarry

    // prologue kk = 1..15 (kbmt = -t4)
    stepf<1>(-t4, ARGS);  stepf<2>(-t4, ARGS);  stepf<3>(-t4, ARGS);
    stepf<4>(-t4, ARGS);  stepf<5>(-t4, ARGS);  stepf<6>(-t4, ARGS);
    stepf<7>(-t4, ARGS);  stepf<8>(-t4, ARGS);  stepf<9>(-t4, ARGS);
    stepf<10>(-t4, ARGS); stepf<11>(-t4, ARGS); stepf<12>(-t4, ARGS);
    stepf<13>(-t4, ARGS); stepf<14>(-t4, ARGS); stepf<15>(-t4, ARGS);

#pragma clang loop unroll(disable)
    for (int kb = 16; kb <= 480; kb += 16) {
        if ((kb & 63) == 0) {
            // block-floating renorm: exact power-of-2, sig -= e
            float M = fmaxf(fmaxf(fmaxf(wA0, wA1), fmaxf(wA2, wA3)),
                            fmaxf(fmaxf(wB0, wB1), fmaxf(wB2, wB3)));
            #pragma unroll
            for (int m = 1; m < 64; m <<= 1) M = fmaxf(M, __shfl_xor(M, m));
            int e = ((__float_as_int(M) >> 23) & 255) - 127;
            float f = __int_as_float((127 - e) << 23);
            wA0 *= f; wA1 *= f; wA2 *= f; wA3 *= f;
            wB0 *= f; wB1 *= f; wB2 *= f; wB3 *= f;
            pdPrev *= f; nxCarry *= f;
            sig -= e;
        }
        const int kbmt = kb - t4;
        stepf<0>(kbmt, ARGS);  stepf<1>(kbmt, ARGS);  stepf<2>(kbmt, ARGS);
        stepf<3>(kbmt, ARGS);  stepf<4>(kbmt, ARGS);  stepf<5>(kbmt, ARGS);
        stepf<6>(kbmt, ARGS);  stepf<7>(kbmt, ARGS);  stepf<8>(kbmt, ARGS);
        stepf<9>(kbmt, ARGS);  stepf<10>(kbmt, ARGS); stepf<11>(kbmt, ARGS);
        stepf<12>(kbmt, ARGS); stepf<13>(kbmt, ARGS); stepf<14>(kbmt, ARGS);
        stepf<15>(kbmt, ARGS);
    }

    // epilogue kk = 496..510 (kbmt = 496 - t4)
    {
        const int kbmt = 496 - t4;
        stepf<0>(kbmt, ARGS);  stepf<1>(kbmt, ARGS);  stepf<2>(kbmt, ARGS);
        stepf<3>(kbmt, ARGS);  stepf<4>(kbmt, ARGS);  stepf<5>(kbmt, ARGS);
        stepf<6>(kbmt, ARGS);  stepf<7>(kbmt, ARGS);  stepf<8>(kbmt, ARGS);
        stepf<9>(kbmt, ARGS);  stepf<10>(kbmt, ARGS); stepf<11>(kbmt, ARGS);
        stepf<12>(kbmt, ARGS); stepf<13>(kbmt, ARGS); stepf<14>(kbmt, ARGS);
    }
#undef ARGS

    // corner (255,255): step 510 is even -> written into B bank; lane 63 wB3
    if (t == 63) out[b] = ((float)sig - LOG2F(wB3)) * LN2;
}

extern "C" void kernel_launch(void* const* d_in, const int* in_sizes, int n_in,
                              void* d_out, int out_size, void* d_ws, size_t ws_size,
                              hipStream_t stream) {
    const float* C = (const float*)d_in[0];
    float* out = (float*)d_out;
    dp_softmin_wave<<<512, 64, 0, stream>>>(C, out);
}